// Round 3
// baseline (478.687 us; speedup 1.0000x reference)
//
#include <hip/hip_runtime.h>
#include <cmath>

typedef unsigned short u16;
typedef unsigned int u32;
typedef short frag8 __attribute__((ext_vector_type(8)));   // 8 bf16 = 4 VGPRs
typedef short frag4v __attribute__((ext_vector_type(4)));  // 4 bf16
typedef float f32x4 __attribute__((ext_vector_type(4)));

#define DEVINL __device__ __forceinline__

DEVINL float bf2f(u16 v) { return __uint_as_float(((u32)v) << 16); }
DEVINL u16 f2bf(float f) {
    u32 u = __float_as_uint(f);
    u32 r = (u + 0x7fffu + ((u >> 16) & 1u)) >> 16;   // RNE
    return (u16)r;
}
DEVINL u32 pack2(float a, float b) { return (u32)f2bf(a) | ((u32)f2bf(b) << 16); }
DEVINL void async_copy16(const u16* g, u16* l) {
    __builtin_amdgcn_global_load_lds((const __attribute__((address_space(1))) u32*)g,
                                     (__attribute__((address_space(3))) u32*)l, 16, 0, 0);
}
DEVINL f32x4 mfma_bf16(frag8 a, frag8 b, f32x4 c) {
    return __builtin_amdgcn_mfma_f32_16x16x32_bf16(a, b, c, 0, 0, 0);
}

// ------------------------------------------------------------------
// Kernel 0: f32 -> bf16 conversion of x, Wq, Wk, Wv, Wout into ws.
// ------------------------------------------------------------------
__global__ __launch_bounds__(256) void convert_kernel(
        const float* __restrict__ s0, const float* __restrict__ s1,
        const float* __restrict__ s2, const float* __restrict__ s3,
        const float* __restrict__ s4, u16* __restrict__ dst) {
    const int c0 = 589824, c1 = 98304, c2 = 98304, c3 = 294912;  // chunks of 8
    const int total = 1376256;
    for (int c = blockIdx.x * blockDim.x + threadIdx.x; c < total;
         c += gridDim.x * blockDim.x) {
        const float* src; int off;
        if (c < c0) { src = s0; off = c; }
        else if (c < c0 + c1) { src = s1; off = c - c0; }
        else if (c < c0 + c1 + c2) { src = s2; off = c - c0 - c1; }
        else if (c < c0 + c1 + c2 + c3) { src = s3; off = c - c0 - c1 - c2; }
        else { src = s4; off = c - c0 - c1 - c2 - c3; }
        float4 a = ((const float4*)src)[off * 2];
        float4 b = ((const float4*)src)[off * 2 + 1];
        uint4 o;
        o.x = pack2(a.x, a.y); o.y = pack2(a.z, a.w);
        o.z = pack2(b.x, b.y); o.w = pack2(b.z, b.w);
        ((uint4*)dst)[c] = o;
    }
}

// ------------------------------------------------------------------
// Kernel 1: positional embedding features fused with rel_k projection
// rel_k layout: [h][3072][64] bf16 (row 3071 = pad, computed anyway)
// ------------------------------------------------------------------
DEVINL double lgamma_stirling(double z) {
    double zi = 1.0 / z, zi2 = zi * zi;
    return (z - 0.5) * log(z) - z + 0.91893853320467274178
         + zi * (1.0 / 12.0) - zi * zi2 * (1.0 / 360.0) + zi * zi2 * zi2 * (1.0 / 1260.0);
}

__global__ __launch_bounds__(256) void embed_relk_kernel(const float* __restrict__ Wrel,
                                                         u16* __restrict__ relk) {
    __shared__ float pos[16][192];
    __shared__ float inv_hl[32], cwid[32], cm1[32], rateS[32];
    __shared__ double lognS[32];
    __shared__ float gmax[16];
    int t = threadIdx.x;
    int u0b = blockIdx.x * 16;

    if (t < 32) {
        double step = (10.584962500721156 - 3.0) / 31.0;   // log2(1536)
        double hl = exp2(3.0 + t * step);
        inv_hl[t] = (float)(1.0 / hl);
        cwid[t] = exp2f((float)(t + 1)) - 1.0f;            // 2^(t+1)-1
        double mean = 48.0 * (t + 1);                      // linspace(48,1536,32)
        double conc = (mean / 24.0) * (mean / 24.0);
        double rate = mean / 576.0;
        cm1[t] = (float)(conc - 1.0);
        rateS[t] = (float)rate;
        lognS[t] = lgamma_stirling(conc) - conc * log(rate);
    }
    __syncthreads();

    for (int idx = t; idx < 512; idx += 256) {
        int ul = idx >> 5, bs = idx & 31;
        int dist = u0b + ul - 1535;
        float ad = fabsf((float)dist);
        pos[ul][bs] = exp2f(-ad * inv_hl[bs]);
        pos[ul][32 + bs] = (cwid[bs] > ad) ? 1.0f : 0.0f;
        double prob = 0.0;
        if (dist != 0) {
            double adD = (double)ad;
            prob = exp((double)cm1[bs] * log(adD) - (double)rateS[bs] * adD - lognS[bs]);
        }
        pos[ul][64 + bs] = (float)(prob + 1e-8);
    }
    __syncthreads();
    if (t < 16) {
        float g = 0.f;
        #pragma unroll
        for (int bsx = 0; bsx < 32; bsx++) g = fmaxf(g, pos[t][64 + bsx]);
        gmax[t] = g;
    }
    __syncthreads();
    for (int idx = t; idx < 16 * 96; idx += 256) {
        int ul = idx / 96, f = idx - ul * 96;
        float v = pos[ul][f];
        if (f >= 64) { v = v / gmax[ul]; pos[ul][f] = v; }
        int dist = u0b + ul - 1535;
        float sg = (dist > 0) ? 1.f : ((dist < 0) ? -1.f : 0.f);
        pos[ul][96 + f] = sg * v;
    }
    __syncthreads();

    // project: rel_k[u][e] = sum_f pos[u][f] * Wrel[e][f]; thread owns 2 e-cols
    int e0 = t * 2;
    const float* w0 = Wrel + e0 * 192;
    const float* w1 = w0 + 192;
    float a0[16], a1[16];
    #pragma unroll
    for (int ul = 0; ul < 16; ul++) { a0[ul] = 0.f; a1[ul] = 0.f; }
    for (int f = 0; f < 192; f++) {
        float wa = w0[f], wb = w1[f];
        #pragma unroll
        for (int ul = 0; ul < 16; ul++) {
            float p = pos[ul][f];
            a0[ul] = fmaf(p, wa, a0[ul]);
            a1[ul] = fmaf(p, wb, a1[ul]);
        }
    }
    int h0 = e0 >> 6, d0 = e0 & 63;
    int h1 = (e0 + 1) >> 6, d1 = (e0 + 1) & 63;
    for (int ul = 0; ul < 16; ul++) {
        int u = u0b + ul;
        relk[(h0 * 3072 + u) * 64 + d0] = f2bf(a0[ul]);
        relk[(h1 * 3072 + u) * 64 + d1] = f2bf(a1[ul]);
    }
}

// ------------------------------------------------------------------
// Shared 128x128 BT-GEMM mainloop (m97 structure), K contiguous in both
// ------------------------------------------------------------------
DEVINL void gemm128_mainloop(const u16* __restrict__ A, const u16* __restrict__ B,
                             int K, f32x4 acc[4][4], u16* As, u16* Bs) {
    int tid = threadIdx.x;
    int lane = tid & 63, wave = tid >> 6;
    int wm = (wave >> 1) * 64, wn = (wave & 1) * 64;
    int fm = lane & 15, fq = lane >> 4;
    for (int k0 = 0; k0 < K; k0 += 32) {
        #pragma unroll
        for (int p = 0; p < 2; p++) {
            int e = (p * 256 + tid) * 8;
            int r = e >> 5, c = e & 31;
            async_copy16(A + r * K + k0 + c, As + e);
            async_copy16(B + r * K + k0 + c, Bs + e);
        }
        __syncthreads();
        frag8 af[4], bfr[4];
        #pragma unroll
        for (int mi = 0; mi < 4; mi++) af[mi] = *(const frag8*)&As[(wm + 16 * mi + fm) * 32 + fq * 8];
        #pragma unroll
        for (int ni = 0; ni < 4; ni++) bfr[ni] = *(const frag8*)&Bs[(wn + 16 * ni + fm) * 32 + fq * 8];
        #pragma unroll
        for (int mi = 0; mi < 4; mi++)
            #pragma unroll
            for (int ni = 0; ni < 4; ni++)
                acc[mi][ni] = mfma_bf16(af[mi], bfr[ni], acc[mi][ni]);
        __syncthreads();
    }
}

// ------------------------------------------------------------------
// Kernel 2: fused QKV projection. N=2560 = [q 512 | k 512 | v 1536]
// qc/qp/k layout [b][h][n][64]; V stored transposed [b][h][192][n]
// ------------------------------------------------------------------
__global__ __launch_bounds__(256) void gemm_qkv_kernel(
        const u16* __restrict__ X, const u16* __restrict__ Wq, const u16* __restrict__ Wk,
        const u16* __restrict__ Wv, const float* __restrict__ cbias, const float* __restrict__ pbias,
        u16* __restrict__ qc, u16* __restrict__ qp, u16* __restrict__ kws, u16* __restrict__ vt) {
    __shared__ __align__(16) u16 As[128 * 32];
    __shared__ __align__(16) u16 Bs[128 * 32];
    int m0 = blockIdx.x * 128, n0 = blockIdx.y * 128;
    const u16* Bp; int brow;
    if (n0 < 512)       { Bp = Wq; brow = n0; }
    else if (n0 < 1024) { Bp = Wk; brow = n0 - 512; }
    else                { Bp = Wv; brow = n0 - 1024; }
    f32x4 acc[4][4];
    #pragma unroll
    for (int i = 0; i < 4; i++)
        #pragma unroll
        for (int j = 0; j < 4; j++) acc[i][j] = (f32x4){0.f, 0.f, 0.f, 0.f};
    gemm128_mainloop(X + m0 * 1536, Bp + brow * 1536, 1536, acc, As, Bs);

    int tid = threadIdx.x, lane = tid & 63, wave = tid >> 6;
    int wm = (wave >> 1) * 64, wn = (wave & 1) * 64, fm = lane & 15, fq = lane >> 4;
    #pragma unroll
    for (int mi = 0; mi < 4; mi++) {
        #pragma unroll
        for (int ni = 0; ni < 4; ni++) {
            int col = n0 + wn + 16 * ni + fm;
            int rbase = m0 + wm + 16 * mi + fq * 4;
            #pragma unroll
            for (int reg = 0; reg < 4; reg++) {
                int row = rbase + reg;
                float v = acc[mi][ni][reg];
                int b = row >= 1536 ? 1 : 0;
                int i = row - b * 1536;
                if (n0 < 512) {
                    float qv = v * 0.125f;
                    int idx = ((b * 8 + (col >> 6)) * 1536 + i) * 64 + (col & 63);
                    qc[idx] = f2bf(qv + cbias[col]);
                    qp[idx] = f2bf(qv + pbias[col]);
                } else if (n0 < 1024) {
                    int c2 = col - 512;
                    kws[((b * 8 + (c2 >> 6)) * 1536 + i) * 64 + (c2 & 63)] = f2bf(v);
                } else {
                    int c2 = col - 1024;
                    int hh = c2 / 192, dd = c2 - hh * 192;
                    vt[((b * 8 + hh) * 192 + dd) * 1536 + i] = f2bf(v);
                }
            }
        }
    }
}

// ------------------------------------------------------------------
// Kernel 3: flash attention, transposed-S formulation.
// BM=32 q-rows/block, BN=64 keys/tile, wave w owns j-cols [16w,16w+16).
// S^T = K·Q^T (MFMA operand swap) -> per-wave online softmax in regs;
// exp'd S^T frag is directly the A-operand for P·V (zero-padded K=32).
// rel band R^T through LDS (pad-34 stride, conflict-free diagonal gather).
// XOR-swizzled staging kills stride-64 fragment-read bank conflicts.
// ------------------------------------------------------------------
__global__ __launch_bounds__(256) void attn_kernel(
        const u16* __restrict__ qc, const u16* __restrict__ qp, const u16* __restrict__ kws,
        const u16* __restrict__ vt, const u16* __restrict__ relk, u16* __restrict__ ao) {
    // LDS carve: k 8192B | vt 24576B | relk 12288B | RT 13056B | mw 512 | lw 512 | Lr 128
    __shared__ __align__(16) u16 smem[29632];
    u16* k_lds    = smem;                  // [64][64] swizzled
    u16* vt_lds   = smem + 4096;           // [192][64] swizzled ([dv][j])
    u16* relk_lds = smem + 16384;          // [96][64] swizzled
    float* RT     = (float*)(smem + 22528);  // [96][34]
    float* mwbuf  = (float*)(smem + 29056);  // [4][2][16]
    float* lwbuf  = mwbuf + 128;
    float* Lr     = lwbuf + 128;             // [32]
    float* Obuf   = (float*)vt_lds;          // epilogue alias: [32][192]

    const int n = 1536;
    int bh = blockIdx.y, b = bh >> 3, h = bh & 7;
    int i0 = blockIdx.x * 32;
    const u16* qcP = qc + bh * n * 64;
    const u16* qpP = qp + bh * n * 64;
    const u16* kP  = kws + bh * n * 64;
    const u16* vtP = vt + bh * 192 * n;
    const u16* rkP = relk + h * 3072 * 64;

    int tid = threadIdx.x, fm = tid & 15, fq = (tid >> 4) & 3, w = tid >> 6;
    int sw = fm & 7;   // xor-swizzle key (= row&7 for all fragment rows)

    // Q fragments (B-operand layout): n-index = i = i0+16mi+fm, k = ks*32+fq*8+e
    frag8 aqc[2][2], aqp[2][2];
    #pragma unroll
    for (int mi = 0; mi < 2; mi++)
        #pragma unroll
        for (int ks = 0; ks < 2; ks++) {
            int off = (i0 + 16 * mi + fm) * 64 + ks * 32 + fq * 8;
            aqc[mi][ks] = *(const frag8*)(qcP + off);
            aqp[mi][ks] = *(const frag8*)(qpP + off);
        }

    f32x4 acc_o[2][12];          // O^(wave): row i_local=fq*4+reg, col dv=16dt+fm
    #pragma unroll
    for (int mi = 0; mi < 2; mi++)
        #pragma unroll
        for (int dt = 0; dt < 12; dt++) acc_o[mi][dt] = (f32x4){0.f, 0.f, 0.f, 0.f};
    float mstate[2] = {__int_as_float(0xff800000), __int_as_float(0xff800000)};
    float lstate[2] = {0.f, 0.f};

    // R-tile ownership: tv = w + 4tt -> (ui = tv%6, rmi = tv/6)
    int uis[3], rmis[3];
    #pragma unroll
    for (int tt = 0; tt < 3; tt++) {
        int tv = w + tt * 4;
        rmis[tt] = (tv >= 6) ? 1 : 0;
        uis[tt] = tv - rmis[tt] * 6;
    }

    for (int jt = 0; jt < 24; jt++) {
        int j0 = jt * 64;
        __syncthreads();   // prior tile's k/vt/relk/RT reads complete
        // ---- staging (xor-swizzled 16B chunks) ----
        #pragma unroll
        for (int p = 0; p < 2; p++) {        // K: 64 rows x 8 chunks
            int l = p * 256 + tid, r = l >> 3, c = (l & 7) ^ (r & 7);
            async_copy16(kP + (j0 + r) * 64 + c * 8, k_lds + l * 8);
        }
        #pragma unroll
        for (int p = 0; p < 6; p++) {        // Vt: 192 rows x 8 chunks
            int l = p * 256 + tid, r = l >> 3, c = (l & 7) ^ (r & 7);
            async_copy16(vtP + r * n + j0 + c * 8, vt_lds + l * 8);
        }
        int u0 = 1504 + j0 - i0;             // band base: u = u0 + jl + 31 - il
        #pragma unroll
        for (int p = 0; p < 3; p++) {        // relk: 96 rows x 8 chunks
            int l = p * 256 + tid, r = l >> 3, c = (l & 7) ^ (r & 7);
            async_copy16(rkP + (u0 + r) * 64 + c * 8, relk_lds + l * 8);
        }
        __syncthreads();   // staging visible

        // ---- S^T = K·Q^T : D[j][i], wave w rows j=16w+{quad*4+reg} ----
        f32x4 acc_s[2];
        acc_s[0] = (f32x4){0.f, 0.f, 0.f, 0.f};
        acc_s[1] = (f32x4){0.f, 0.f, 0.f, 0.f};
        #pragma unroll
        for (int ks = 0; ks < 2; ks++) {
            frag8 kf = *(const frag8*)&k_lds[(16 * w + fm) * 64 + ((ks * 4 + fq) ^ sw) * 8];
            acc_s[0] = mfma_bf16(kf, aqc[0][ks], acc_s[0]);
            acc_s[1] = mfma_bf16(kf, aqc[1][ks], acc_s[1]);
        }
        // ---- R^T = relk·qp^T : D[u'][i], write shared RT[96][34] ----
        #pragma unroll
        for (int tt = 0; tt < 3; tt++) {
            f32x4 r = (f32x4){0.f, 0.f, 0.f, 0.f};
            #pragma unroll
            for (int ks = 0; ks < 2; ks++) {
                frag8 rf = *(const frag8*)&relk_lds[(16 * uis[tt] + fm) * 64 + ((ks * 4 + fq) ^ sw) * 8];
                r = mfma_bf16(rf, aqp[rmis[tt]][ks], r);
            }
            #pragma unroll
            for (int reg = 0; reg < 4; reg++)
                RT[(16 * uis[tt] + fq * 4 + reg) * 34 + 16 * rmis[tt] + fm] = r[reg];
        }
        __syncthreads();   // RT visible

        // ---- per-wave online softmax in registers ----
        frag8 ap[2];
        #pragma unroll
        for (int mi = 0; mi < 2; mi++) {
            int i_full = 16 * mi + fm;
            float sv[4];
            float mx = __int_as_float(0xff800000);
            #pragma unroll
            for (int reg = 0; reg < 4; reg++) {
                int up = 16 * w + fq * 4 + reg + 31 - i_full;   // u' = jl+31-il
                sv[reg] = acc_s[mi][reg] + RT[up * 34 + i_full];
                mx = fmaxf(mx, sv[reg]);
            }
            mx = fmaxf(mx, __shfl_xor(mx, 16));
            mx = fmaxf(mx, __shfl_xor(mx, 32));
            float mn = fmaxf(mstate[mi], mx);
            float al = __expf(mstate[mi] - mn);
            mstate[mi] = mn;
            float pv[4], psum = 0.f;
            #pragma unroll
            for (int reg = 0; reg < 4; reg++) { pv[reg] = __expf(sv[reg] - mn); psum += pv[reg]; }
            psum += __shfl_xor(psum, 16);
            psum += __shfl_xor(psum, 32);
            lstate[mi] = lstate[mi] * al + psum;
            // P fragment = A-operand (zero-padded upper K): k = quad*8+e, e<4 used
            ap[mi] = (frag8){(short)f2bf(pv[0]), (short)f2bf(pv[1]),
                             (short)f2bf(pv[2]), (short)f2bf(pv[3]), 0, 0, 0, 0};
            // alpha broadcast to O-layout rows (i_row = fq*4+reg) via dynamic shfl
            #pragma unroll
            for (int reg = 0; reg < 4; reg++) {
                float ab = __shfl(al, fq * 4 + reg);
                #pragma unroll
                for (int dt = 0; dt < 12; dt++) acc_o[mi][dt][reg] *= ab;
            }
        }

        // ---- P·V : B = V[k=j][n=dv] from swizzled vt_lds[dv][j] ----
        int cj = 2 * w + (fq >> 1);          // source j-chunk for this quad
        int jo = (fq & 1) * 4;               // offset within chunk
        #pragma unroll
        for (int dt = 0; dt < 12; dt++) {
            frag4v t4 = *(const frag4v*)&vt_lds[(16 * dt + fm) * 64 + (cj ^ sw) * 8 + jo];
            frag8 bv = (frag8){t4[0], t4[1], t4[2], t4[3], 0, 0, 0, 0};
            acc_o[0][dt] = mfma_bf16(ap[0], bv, acc_o[0][dt]);
            acc_o[1][dt] = mfma_bf16(ap[1], bv, acc_o[1][dt]);
        }
    }

    // ---- epilogue: merge 4 per-wave (m,l,O) states ----
    __syncthreads();   // last PV reads done; vt_lds retired
    if (fq == 0) {
        #pragma unroll
        for (int mi = 0; mi < 2; mi++) {
            mwbuf[(w * 2 + mi) * 16 + fm] = mstate[mi];
            lwbuf[(w * 2 + mi) * 16 + fm] = lstate[mi];
        }
    }
    #pragma unroll
    for (int r = 0; r < 24; r++) Obuf[r * 256 + tid] = 0.f;
    __syncthreads();
    #pragma unroll
    for (int mi = 0; mi < 2; mi++)
        #pragma unroll
        for (int reg = 0; reg < 4; reg++) {
            int ir = fq * 4 + reg;
            float mg = mwbuf[mi * 16 + ir];
            #pragma unroll
            for (int wv = 1; wv < 4; wv++) mg = fmaxf(mg, mwbuf[(wv * 2 + mi) * 16 + ir]);
            float sc = __expf(mwbuf[(w * 2 + mi) * 16 + ir] - mg);
            #pragma unroll
            for (int dt = 0; dt < 12; dt++)
                atomicAdd(&Obuf[(16 * mi + ir) * 192 + 16 * dt + fm], acc_o[mi][dt][reg] * sc);
        }
    __syncthreads();
    if (tid < 32) {
        int mi = tid >> 4, ir = tid & 15;
        float mg = mwbuf[mi * 16 + ir];
        #pragma unroll
        for (int wv = 1; wv < 4; wv++) mg = fmaxf(mg, mwbuf[(wv * 2 + mi) * 16 + ir]);
        float L = 0.f;
        #pragma unroll
        for (int wv = 0; wv < 4; wv++)
            L += lwbuf[(wv * 2 + mi) * 16 + ir] * __expf(mwbuf[(wv * 2 + mi) * 16 + ir] - mg);
        Lr[tid] = 1.0f / L;
    }
    __syncthreads();
    for (int r = 0; r < 24; r++) {
        int idx = r * 256 + tid;
        int i = idx / 192, dv = idx - i * 192;
        ao[(b * 1536 + i0 + i) * 1536 + h * 192 + dv] = f2bf(Obuf[idx] * Lr[i]);
    }
}

// ------------------------------------------------------------------
// Kernel 4: output projection + bias (f32 out)
// ------------------------------------------------------------------
__global__ __launch_bounds__(256) void gemm_out_kernel(
        const u16* __restrict__ A, const u16* __restrict__ W, const float* __restrict__ bias,
        float* __restrict__ out) {
    __shared__ __align__(16) u16 As[128 * 32];
    __shared__ __align__(16) u16 Bs[128 * 32];
    int m0 = blockIdx.x * 128, n0 = blockIdx.y * 128;
    f32x4 acc[4][4];
    #pragma unroll
    for (int i = 0; i < 4; i++)
        #pragma unroll
        for (int j = 0; j < 4; j++) acc[i][j] = (f32x4){0.f, 0.f, 0.f, 0.f};
    gemm128_mainloop(A + m0 * 1536, W + n0 * 1536, 1536, acc, As, Bs);

    int tid = threadIdx.x, lane = tid & 63, wave = tid >> 6;
    int wm = (wave >> 1) * 64, wn = (wave & 1) * 64, fm = lane & 15, fq = lane >> 4;
    #pragma unroll
    for (int mi = 0; mi < 4; mi++) {
        #pragma unroll
        for (int ni = 0; ni < 4; ni++) {
            int col = n0 + wn + 16 * ni + fm;
            int rbase = m0 + wm + 16 * mi + fq * 4;
            float bv = bias[col];
            #pragma unroll
            for (int reg = 0; reg < 4; reg++) {
                int row = rbase + reg;
                out[row * 1536 + col] = acc[mi][ni][reg] + bv;
            }
        }
    }
}

// ------------------------------------------------------------------
extern "C" void kernel_launch(void* const* d_in, const int* in_sizes, int n_in,
                              void* d_out, int out_size, void* d_ws, size_t ws_size,
                              hipStream_t stream) {
    (void)in_sizes; (void)n_in; (void)out_size; (void)ws_size;
    const float* x    = (const float*)d_in[0];
    const float* Wq   = (const float*)d_in[1];
    const float* Wk   = (const float*)d_in[2];
    const float* Wv   = (const float*)d_in[3];
    const float* Wrel = (const float*)d_in[4];
    const float* Wout = (const float*)d_in[5];
    const float* bout = (const float*)d_in[6];
    const float* cb   = (const float*)d_in[7];
    const float* pb   = (const float*)d_in[8];

    // bf16 workspace layout (u16 units)
    u16* xb  = (u16*)d_ws;                // 2*1536*1536 = 4,718,592
    u16* wqb = xb  + 4718592;             // 512*1536    =   786,432
    u16* wkb = wqb + 786432;              //               786,432
    u16* wvb = wkb + 786432;              // 1536*1536   = 2,359,296
    u16* wob = wvb + 2359296;             // 1536*1536   = 2,359,296
    u16* qc  = wob + 2359296;             // 2*8*1536*64 = 1,572,864
    u16* qp  = qc + 1572864;
    u16* kw  = qp + 1572864;
    u16* vt  = kw + 1572864;              // 2*8*192*1536 = 4,718,592
    u16* rk  = vt + 4718592;              // 8*3072*64    = 1,572,864
    u16* ao  = rk + 1572864;              // 3072*1536    = 4,718,592
    float* out = (float*)d_out;

    convert_kernel<<<dim3(1024), dim3(256), 0, stream>>>(x, Wq, Wk, Wv, Wout, xb);
    embed_relk_kernel<<<dim3(192), dim3(256), 0, stream>>>(Wrel, rk);
    gemm_qkv_kernel<<<dim3(24, 20), dim3(256), 0, stream>>>(xb, wqb, wkb, wvb, cb, pb, qc, qp, kw, vt);
    attn_kernel<<<dim3(48, 16), dim3(256), 0, stream>>>(qc, qp, kw, vt, rk, ao);
    gemm_out_kernel<<<dim3(24, 12), dim3(256), 0, stream>>>(ao, wob, bout, out);
}

// Round 4
// 328.226 us; speedup vs baseline: 1.4584x; 1.4584x over previous
//
#include <hip/hip_runtime.h>
#include <cmath>

typedef unsigned short u16;
typedef unsigned int u32;
typedef short frag8 __attribute__((ext_vector_type(8)));   // 8 bf16 = 4 VGPRs
typedef float f32x4 __attribute__((ext_vector_type(4)));

#define DEVINL __device__ __forceinline__

DEVINL float bf2f(u16 v) { return __uint_as_float(((u32)v) << 16); }
DEVINL u16 f2bf(float f) {
    u32 u = __float_as_uint(f);
    u32 r = (u + 0x7fffu + ((u >> 16) & 1u)) >> 16;   // RNE
    return (u16)r;
}
DEVINL u32 pack2(float a, float b) { return (u32)f2bf(a) | ((u32)f2bf(b) << 16); }
DEVINL void async_copy16(const u16* g, u16* l) {
    __builtin_amdgcn_global_load_lds((const __attribute__((address_space(1))) u32*)g,
                                     (__attribute__((address_space(3))) u32*)l, 16, 0, 0);
}
DEVINL f32x4 mfma_bf16(frag8 a, frag8 b, f32x4 c) {
    return __builtin_amdgcn_mfma_f32_16x16x32_bf16(a, b, c, 0, 0, 0);
}

// ------------------------------------------------------------------
// Kernel 0: f32 -> bf16 conversion of x, Wq, Wk, Wv, Wout into ws.
// ------------------------------------------------------------------
__global__ __launch_bounds__(256) void convert_kernel(
        const float* __restrict__ s0, const float* __restrict__ s1,
        const float* __restrict__ s2, const float* __restrict__ s3,
        const float* __restrict__ s4, u16* __restrict__ dst) {
    const int c0 = 589824, c1 = 98304, c2 = 98304, c3 = 294912;  // chunks of 8
    const int total = 1376256;
    for (int c = blockIdx.x * blockDim.x + threadIdx.x; c < total;
         c += gridDim.x * blockDim.x) {
        const float* src; int off;
        if (c < c0) { src = s0; off = c; }
        else if (c < c0 + c1) { src = s1; off = c - c0; }
        else if (c < c0 + c1 + c2) { src = s2; off = c - c0 - c1; }
        else if (c < c0 + c1 + c2 + c3) { src = s3; off = c - c0 - c1 - c2; }
        else { src = s4; off = c - c0 - c1 - c2 - c3; }
        float4 a = ((const float4*)src)[off * 2];
        float4 b = ((const float4*)src)[off * 2 + 1];
        uint4 o;
        o.x = pack2(a.x, a.y); o.y = pack2(a.z, a.w);
        o.z = pack2(b.x, b.y); o.w = pack2(b.z, b.w);
        ((uint4*)dst)[c] = o;
    }
}

// ------------------------------------------------------------------
// Kernel 1: positional embedding features fused with rel_k projection
// rel_k layout: [h][3072][64] bf16 (row 3071 = pad, computed anyway)
// ------------------------------------------------------------------
DEVINL double lgamma_stirling(double z) {
    double zi = 1.0 / z, zi2 = zi * zi;
    return (z - 0.5) * log(z) - z + 0.91893853320467274178
         + zi * (1.0 / 12.0) - zi * zi2 * (1.0 / 360.0) + zi * zi2 * zi2 * (1.0 / 1260.0);
}

__global__ __launch_bounds__(256) void embed_relk_kernel(const float* __restrict__ Wrel,
                                                         u16* __restrict__ relk) {
    __shared__ float pos[16][192];
    __shared__ float inv_hl[32], cwid[32], cm1[32], rateS[32];
    __shared__ double lognS[32];
    __shared__ float gmax[16];
    int t = threadIdx.x;
    int u0b = blockIdx.x * 16;

    if (t < 32) {
        double step = (10.584962500721156 - 3.0) / 31.0;   // log2(1536)
        double hl = exp2(3.0 + t * step);
        inv_hl[t] = (float)(1.0 / hl);
        cwid[t] = exp2f((float)(t + 1)) - 1.0f;            // 2^(t+1)-1
        double mean = 48.0 * (t + 1);                      // linspace(48,1536,32)
        double conc = (mean / 24.0) * (mean / 24.0);
        double rate = mean / 576.0;
        cm1[t] = (float)(conc - 1.0);
        rateS[t] = (float)rate;
        lognS[t] = lgamma_stirling(conc) - conc * log(rate);
    }
    __syncthreads();

    for (int idx = t; idx < 512; idx += 256) {
        int ul = idx >> 5, bs = idx & 31;
        int dist = u0b + ul - 1535;
        float ad = fabsf((float)dist);
        pos[ul][bs] = exp2f(-ad * inv_hl[bs]);
        pos[ul][32 + bs] = (cwid[bs] > ad) ? 1.0f : 0.0f;
        double prob = 0.0;
        if (dist != 0) {
            double adD = (double)ad;
            prob = exp((double)cm1[bs] * log(adD) - (double)rateS[bs] * adD - lognS[bs]);
        }
        pos[ul][64 + bs] = (float)(prob + 1e-8);
    }
    __syncthreads();
    if (t < 16) {
        float g = 0.f;
        #pragma unroll
        for (int bsx = 0; bsx < 32; bsx++) g = fmaxf(g, pos[t][64 + bsx]);
        gmax[t] = g;
    }
    __syncthreads();
    for (int idx = t; idx < 16 * 96; idx += 256) {
        int ul = idx / 96, f = idx - ul * 96;
        float v = pos[ul][f];
        if (f >= 64) { v = v / gmax[ul]; pos[ul][f] = v; }
        int dist = u0b + ul - 1535;
        float sg = (dist > 0) ? 1.f : ((dist < 0) ? -1.f : 0.f);
        pos[ul][96 + f] = sg * v;
    }
    __syncthreads();

    // project: rel_k[u][e] = sum_f pos[u][f] * Wrel[e][f]; thread owns 2 e-cols
    int e0 = t * 2;
    const float* w0 = Wrel + e0 * 192;
    const float* w1 = w0 + 192;
    float a0[16], a1[16];
    #pragma unroll
    for (int ul = 0; ul < 16; ul++) { a0[ul] = 0.f; a1[ul] = 0.f; }
    for (int f = 0; f < 192; f++) {
        float wa = w0[f], wb = w1[f];
        #pragma unroll
        for (int ul = 0; ul < 16; ul++) {
            float p = pos[ul][f];
            a0[ul] = fmaf(p, wa, a0[ul]);
            a1[ul] = fmaf(p, wb, a1[ul]);
        }
    }
    int h0 = e0 >> 6, d0 = e0 & 63;
    int h1 = (e0 + 1) >> 6, d1 = (e0 + 1) & 63;
    for (int ul = 0; ul < 16; ul++) {
        int u = u0b + ul;
        relk[(h0 * 3072 + u) * 64 + d0] = f2bf(a0[ul]);
        relk[(h1 * 3072 + u) * 64 + d1] = f2bf(a1[ul]);
    }
}

// ------------------------------------------------------------------
// Shared 128x128 BT-GEMM mainloop (m97 structure), K contiguous in both
// ------------------------------------------------------------------
DEVINL void gemm128_mainloop(const u16* __restrict__ A, const u16* __restrict__ B,
                             int K, f32x4 acc[4][4], u16* As, u16* Bs) {
    int tid = threadIdx.x;
    int lane = tid & 63, wave = tid >> 6;
    int wm = (wave >> 1) * 64, wn = (wave & 1) * 64;
    int fm = lane & 15, fq = lane >> 4;
    for (int k0 = 0; k0 < K; k0 += 32) {
        #pragma unroll
        for (int p = 0; p < 2; p++) {
            int e = (p * 256 + tid) * 8;
            int r = e >> 5, c = e & 31;
            async_copy16(A + r * K + k0 + c, As + e);
            async_copy16(B + r * K + k0 + c, Bs + e);
        }
        __syncthreads();
        frag8 af[4], bfr[4];
        #pragma unroll
        for (int mi = 0; mi < 4; mi++) af[mi] = *(const frag8*)&As[(wm + 16 * mi + fm) * 32 + fq * 8];
        #pragma unroll
        for (int ni = 0; ni < 4; ni++) bfr[ni] = *(const frag8*)&Bs[(wn + 16 * ni + fm) * 32 + fq * 8];
        #pragma unroll
        for (int mi = 0; mi < 4; mi++)
            #pragma unroll
            for (int ni = 0; ni < 4; ni++)
                acc[mi][ni] = mfma_bf16(af[mi], bfr[ni], acc[mi][ni]);
        __syncthreads();
    }
}

// ------------------------------------------------------------------
// Kernel 2: fused QKV projection. N=2560 = [q 512 | k 512 | v 1536]
// qc/qp/k layout [b][h][n][64]; V stored transposed [b][h][192][n]
// ------------------------------------------------------------------
__global__ __launch_bounds__(256) void gemm_qkv_kernel(
        const u16* __restrict__ X, const u16* __restrict__ Wq, const u16* __restrict__ Wk,
        const u16* __restrict__ Wv, const float* __restrict__ cbias, const float* __restrict__ pbias,
        u16* __restrict__ qc, u16* __restrict__ qp, u16* __restrict__ kws, u16* __restrict__ vt) {
    __shared__ __align__(16) u16 As[128 * 32];
    __shared__ __align__(16) u16 Bs[128 * 32];
    int m0 = blockIdx.x * 128, n0 = blockIdx.y * 128;
    const u16* Bp; int brow;
    if (n0 < 512)       { Bp = Wq; brow = n0; }
    else if (n0 < 1024) { Bp = Wk; brow = n0 - 512; }
    else                { Bp = Wv; brow = n0 - 1024; }
    f32x4 acc[4][4];
    #pragma unroll
    for (int i = 0; i < 4; i++)
        #pragma unroll
        for (int j = 0; j < 4; j++) acc[i][j] = (f32x4){0.f, 0.f, 0.f, 0.f};
    gemm128_mainloop(X + m0 * 1536, Bp + brow * 1536, 1536, acc, As, Bs);

    int tid = threadIdx.x, lane = tid & 63, wave = tid >> 6;
    int wm = (wave >> 1) * 64, wn = (wave & 1) * 64, fm = lane & 15, fq = lane >> 4;
    #pragma unroll
    for (int mi = 0; mi < 4; mi++) {
        #pragma unroll
        for (int ni = 0; ni < 4; ni++) {
            int col = n0 + wn + 16 * ni + fm;
            int rbase = m0 + wm + 16 * mi + fq * 4;
            #pragma unroll
            for (int reg = 0; reg < 4; reg++) {
                int row = rbase + reg;
                float v = acc[mi][ni][reg];
                int b = row >= 1536 ? 1 : 0;
                int i = row - b * 1536;
                if (n0 < 512) {
                    float qv = v * 0.125f;
                    int idx = ((b * 8 + (col >> 6)) * 1536 + i) * 64 + (col & 63);
                    qc[idx] = f2bf(qv + cbias[col]);
                    qp[idx] = f2bf(qv + pbias[col]);
                } else if (n0 < 1024) {
                    int c2 = col - 512;
                    kws[((b * 8 + (c2 >> 6)) * 1536 + i) * 64 + (c2 & 63)] = f2bf(v);
                } else {
                    int c2 = col - 1024;
                    int hh = c2 / 192, dd = c2 - hh * 192;
                    vt[((b * 8 + hh) * 192 + dd) * 1536 + i] = f2bf(v);
                }
            }
        }
    }
}

// ------------------------------------------------------------------
// Kernel 3: flash attention with relative-shift band (round-2 structure
// + xor-swizzled staging/frag reads + S-over-K LDS alias for 3 blocks/CU).
// BM=32 q-rows, BN=64 keys/tile. rel[i,j] = qp_i . relk[n-1+j-i]
// ------------------------------------------------------------------
__global__ __launch_bounds__(256) void attn_kernel(
        const u16* __restrict__ qc, const u16* __restrict__ qp, const u16* __restrict__ kws,
        const u16* __restrict__ vt, const u16* __restrict__ relk, u16* __restrict__ ao) {
    // carve (u16 units): k 4096 | vt 12288 | relk 6144 | P 2048 | state 192
    // total 24768 u16 = 49536 B  -> 3 blocks/CU
    __shared__ __align__(16) u16 smem[24768];
    u16* k_lds    = smem;                    // [64][64] swizzled; aliased S[32][64] f32
    u16* vt_lds   = smem + 4096;             // [192][64] swizzled ([dv][j])
    u16* relk_lds = smem + 16384;            // [96][64] swizzled; aliased R[32][96] f32
    u16* P_lds    = smem + 22528;            // [32][64], chunk-swizzled
    float* S_lds  = (float*)k_lds;
    float* R_lds  = (float*)relk_lds;
    float* mstate = (float*)(smem + 24576);  // [32]
    float* lstate = mstate + 32;
    float* alpha_lds = lstate + 32;

    const int n = 1536;
    int bh = blockIdx.y, b = bh >> 3, h = bh & 7;
    int i0 = blockIdx.x * 32;
    const u16* qcP = qc + bh * n * 64;
    const u16* qpP = qp + bh * n * 64;
    const u16* kP  = kws + bh * n * 64;
    const u16* vtP = vt + bh * 192 * n;
    const u16* rkP = relk + h * 3072 * 64;

    int tid = threadIdx.x, lane = tid & 63, w = tid >> 6, fm = lane & 15, fq = lane >> 4;
    int sw = fm & 7;   // xor-swizzle key: row&7 == fm&7 for all fragment rows
    if (tid < 32) { mstate[tid] = __int_as_float(0xff800000); lstate[tid] = 0.f; }

    // Q fragments live in registers for the whole block
    frag8 aqc[2][2], aqp[2][2];
    #pragma unroll
    for (int mi = 0; mi < 2; mi++)
        #pragma unroll
        for (int ks = 0; ks < 2; ks++) {
            int off = (i0 + 16 * mi + fm) * 64 + ks * 32 + fq * 8;
            aqc[mi][ks] = *(const frag8*)(qcP + off);
            aqp[mi][ks] = *(const frag8*)(qpP + off);
        }

    f32x4 acc_o[2][3];
    #pragma unroll
    for (int mi = 0; mi < 2; mi++)
        #pragma unroll
        for (int dj = 0; dj < 3; dj++) acc_o[mi][dj] = (f32x4){0.f, 0.f, 0.f, 0.f};

    // R-tile ownership: tv = w + 4tt -> (ui = tv%6, rmi = tv/6)
    int uis[3], rmis[3];
    #pragma unroll
    for (int tt = 0; tt < 3; tt++) {
        int tv = w + tt * 4;
        rmis[tt] = (tv >= 6) ? 1 : 0;
        uis[tt] = tv - rmis[tt] * 6;
    }

    for (int jt = 0; jt < 24; jt++) {
        int j0 = jt * 64;
        __syncthreads();   // B1: prior tile's LDS reads complete
        // ---- staging, xor-swizzled 16B chunks ----
        #pragma unroll
        for (int p = 0; p < 2; p++) {        // K: 64 rows x 8 chunks
            int l = p * 256 + tid, r = l >> 3, c = (l & 7) ^ (r & 7);
            async_copy16(kP + (j0 + r) * 64 + c * 8, k_lds + l * 8);
        }
        #pragma unroll
        for (int p = 0; p < 6; p++) {        // Vt: 192 rows x 8 chunks
            int l = p * 256 + tid, r = l >> 3, c = (l & 7) ^ (r & 7);
            async_copy16(vtP + r * n + j0 + c * 8, vt_lds + l * 8);
        }
        int u0 = 1504 + j0 - i0;             // u = u0 + (j-j0) + 31 - (i-i0)
        #pragma unroll
        for (int p = 0; p < 3; p++) {        // relk: 96 rows x 8 chunks
            int l = p * 256 + tid, r = l >> 3, c = (l & 7) ^ (r & 7);
            async_copy16(rkP + (u0 + r) * 64 + c * 8, relk_lds + l * 8);
        }
        __syncthreads();   // B2: staging visible

        // content logits: wave w owns j-cols 16w..16w+15
        f32x4 acc_s[2];
        acc_s[0] = (f32x4){0.f, 0.f, 0.f, 0.f};
        acc_s[1] = (f32x4){0.f, 0.f, 0.f, 0.f};
        #pragma unroll
        for (int ks = 0; ks < 2; ks++) {
            frag8 bk = *(const frag8*)&k_lds[(16 * w + fm) * 64 + ((ks * 4 + fq) ^ sw) * 8];
            acc_s[0] = mfma_bf16(aqc[0][ks], bk, acc_s[0]);
            acc_s[1] = mfma_bf16(aqc[1][ks], bk, acc_s[1]);
        }
        // rel band R[32][96]: 12 tiles, wave w owns tv = w, w+4, w+8
        f32x4 acc_r[3];
        #pragma unroll
        for (int tt = 0; tt < 3; tt++) {
            acc_r[tt] = (f32x4){0.f, 0.f, 0.f, 0.f};
            #pragma unroll
            for (int ks = 0; ks < 2; ks++) {
                frag8 br = *(const frag8*)&relk_lds[(16 * uis[tt] + fm) * 64 + ((ks * 4 + fq) ^ sw) * 8];
                acc_r[tt] = mfma_bf16(aqp[rmis[tt]][ks], br, acc_r[tt]);
            }
        }
        __syncthreads();   // B3: k/relk reads done; safe to overwrite with S/R

        #pragma unroll
        for (int mi = 0; mi < 2; mi++)
            #pragma unroll
            for (int reg = 0; reg < 4; reg++)
                S_lds[(16 * mi + fq * 4 + reg) * 64 + 16 * w + fm] = acc_s[mi][reg];
        #pragma unroll
        for (int tt = 0; tt < 3; tt++)
            #pragma unroll
            for (int reg = 0; reg < 4; reg++)
                R_lds[(16 * rmis[tt] + fq * 4 + reg) * 96 + 16 * uis[tt] + fm] = acc_r[tt][reg];
        __syncthreads();   // B4: S and R visible

        // online softmax: 8 threads per row; P chunk-swizzled write
        int li = tid >> 3, c0 = (tid & 7) * 8;
        float sv[8];
        float mx = __int_as_float(0xff800000);
        #pragma unroll
        for (int e = 0; e < 8; e++) {
            int c = c0 + e;
            sv[e] = S_lds[li * 64 + c] + R_lds[li * 96 + c - li + 31];
            mx = fmaxf(mx, sv[e]);
        }
        mx = fmaxf(mx, __shfl_xor(mx, 1));
        mx = fmaxf(mx, __shfl_xor(mx, 2));
        mx = fmaxf(mx, __shfl_xor(mx, 4));
        float mo = mstate[li];
        float mn = fmaxf(mo, mx);
        float al = __expf(mo - mn);
        float pe[8], sum = 0.f;
        #pragma unroll
        for (int e = 0; e < 8; e++) { pe[e] = __expf(sv[e] - mn); sum += pe[e]; }
        {
            uint4 pw;
            pw.x = pack2(pe[0], pe[1]); pw.y = pack2(pe[2], pe[3]);
            pw.z = pack2(pe[4], pe[5]); pw.w = pack2(pe[6], pe[7]);
            int slot = (tid & 7) ^ (li & 7);
            *(uint4*)&P_lds[li * 64 + slot * 8] = pw;
        }
        sum += __shfl_xor(sum, 1);
        sum += __shfl_xor(sum, 2);
        sum += __shfl_xor(sum, 4);
        if ((tid & 7) == 0) {
            mstate[li] = mn;
            lstate[li] = lstate[li] * al + sum;
            alpha_lds[li] = al;
        }
        __syncthreads();   // B5: P, alpha visible

        // PV: wave w owns dv tiles 3w..3w+2
        #pragma unroll
        for (int mi = 0; mi < 2; mi++)
            #pragma unroll
            for (int reg = 0; reg < 4; reg++) {
                float al2 = alpha_lds[16 * mi + fq * 4 + reg];
                #pragma unroll
                for (int dj = 0; dj < 3; dj++) acc_o[mi][dj][reg] *= al2;
            }
        frag8 ap[2][2];
        #pragma unroll
        for (int mi = 0; mi < 2; mi++)
            #pragma unroll
            for (int ks = 0; ks < 2; ks++)
                ap[mi][ks] = *(const frag8*)&P_lds[(16 * mi + fm) * 64 + ((ks * 4 + fq) ^ sw) * 8];
        #pragma unroll
        for (int dj = 0; dj < 3; dj++) {
            #pragma unroll
            for (int ks = 0; ks < 2; ks++) {
                frag8 bv = *(const frag8*)&vt_lds[(16 * (3 * w + dj) + fm) * 64 + ((ks * 4 + fq) ^ sw) * 8];
                acc_o[0][dj] = mfma_bf16(ap[0][ks], bv, acc_o[0][dj]);
                acc_o[1][dj] = mfma_bf16(ap[1][ks], bv, acc_o[1][dj]);
            }
        }
    }

    // epilogue: O / l -> ao[b*1536 + i][h*192 + dv]
    __syncthreads();
    #pragma unroll
    for (int mi = 0; mi < 2; mi++)
        #pragma unroll
        for (int dj = 0; dj < 3; dj++)
            #pragma unroll
            for (int reg = 0; reg < 4; reg++) {
                int rl = 16 * mi + fq * 4 + reg;
                float lsum = lstate[rl];
                int row = b * 1536 + i0 + rl;
                int col = h * 192 + 16 * (3 * w + dj) + fm;
                ao[row * 1536 + col] = f2bf(acc_o[mi][dj][reg] / lsum);
            }
}

// ------------------------------------------------------------------
// Kernel 4: output projection + bias (f32 out)
// ------------------------------------------------------------------
__global__ __launch_bounds__(256) void gemm_out_kernel(
        const u16* __restrict__ A, const u16* __restrict__ W, const float* __restrict__ bias,
        float* __restrict__ out) {
    __shared__ __align__(16) u16 As[128 * 32];
    __shared__ __align__(16) u16 Bs[128 * 32];
    int m0 = blockIdx.x * 128, n0 = blockIdx.y * 128;
    f32x4 acc[4][4];
    #pragma unroll
    for (int i = 0; i < 4; i++)
        #pragma unroll
        for (int j = 0; j < 4; j++) acc[i][j] = (f32x4){0.f, 0.f, 0.f, 0.f};
    gemm128_mainloop(A + m0 * 1536, W + n0 * 1536, 1536, acc, As, Bs);

    int tid = threadIdx.x, lane = tid & 63, wave = tid >> 6;
    int wm = (wave >> 1) * 64, wn = (wave & 1) * 64, fm = lane & 15, fq = lane >> 4;
    #pragma unroll
    for (int mi = 0; mi < 4; mi++) {
        #pragma unroll
        for (int ni = 0; ni < 4; ni++) {
            int col = n0 + wn + 16 * ni + fm;
            int rbase = m0 + wm + 16 * mi + fq * 4;
            float bv = bias[col];
            #pragma unroll
            for (int reg = 0; reg < 4; reg++) {
                int row = rbase + reg;
                out[row * 1536 + col] = acc[mi][ni][reg] + bv;
            }
        }
    }
}

// ------------------------------------------------------------------
extern "C" void kernel_launch(void* const* d_in, const int* in_sizes, int n_in,
                              void* d_out, int out_size, void* d_ws, size_t ws_size,
                              hipStream_t stream) {
    (void)in_sizes; (void)n_in; (void)out_size; (void)ws_size;
    const float* x    = (const float*)d_in[0];
    const float* Wq   = (const float*)d_in[1];
    const float* Wk   = (const float*)d_in[2];
    const float* Wv   = (const float*)d_in[3];
    const float* Wrel = (const float*)d_in[4];
    const float* Wout = (const float*)d_in[5];
    const float* bout = (const float*)d_in[6];
    const float* cb   = (const float*)d_in[7];
    const float* pb   = (const float*)d_in[8];

    // bf16 workspace layout (u16 units)
    u16* xb  = (u16*)d_ws;                // 2*1536*1536 = 4,718,592
    u16* wqb = xb  + 4718592;             // 512*1536    =   786,432
    u16* wkb = wqb + 786432;              //               786,432
    u16* wvb = wkb + 786432;              // 1536*1536   = 2,359,296
    u16* wob = wvb + 2359296;             // 1536*1536   = 2,359,296
    u16* qc  = wob + 2359296;             // 2*8*1536*64 = 1,572,864
    u16* qp  = qc + 1572864;
    u16* kw  = qp + 1572864;
    u16* vt  = kw + 1572864;              // 2*8*192*1536 = 4,718,592
    u16* rk  = vt + 4718592;              // 8*3072*64    = 1,572,864
    u16* ao  = rk + 1572864;              // 3072*1536    = 4,718,592
    float* out = (float*)d_out;

    convert_kernel<<<dim3(1024), dim3(256), 0, stream>>>(x, Wq, Wk, Wv, Wout, xb);
    embed_relk_kernel<<<dim3(192), dim3(256), 0, stream>>>(Wrel, rk);
    gemm_qkv_kernel<<<dim3(24, 20), dim3(256), 0, stream>>>(xb, wqb, wkb, wvb, cb, pb, qc, qp, kw, vt);
    attn_kernel<<<dim3(48, 16), dim3(256), 0, stream>>>(qc, qp, kw, vt, rk, ao);
    gemm_out_kernel<<<dim3(24, 12), dim3(256), 0, stream>>>(ao, wob, bout, out);
}